// Round 6
// baseline (431.244 us; speedup 1.0000x reference)
//
#include <hip/hip_runtime.h>

typedef __bf16 bf16x8 __attribute__((ext_vector_type(8)));
typedef float f32x4 __attribute__((ext_vector_type(4)));

#define MFMA16(a, b, c) __builtin_amdgcn_mfma_f32_16x16x32_bf16(a, b, c, 0, 0, 0)
#define LOG2E 1.44269504088896340736f

__device__ __forceinline__ unsigned short f2bf(float f) {
  union { float f; unsigned u; } v; v.f = f;
  return (unsigned short)((v.u + 0x7fffu + ((v.u >> 16) & 1u)) >> 16);
}
__device__ __forceinline__ bf16x8 ld_frag(const unsigned short* p) {
  return *(const bf16x8*)p;  // 16B-aligned by construction
}
__device__ __forceinline__ void gld_lds16(const unsigned short* g, unsigned short* l) {
  __builtin_amdgcn_global_load_lds(
      (const __attribute__((address_space(1))) unsigned int*)(const void*)g,
      (__attribute__((address_space(3))) unsigned int*)(void*)l, 16, 0, 0);
}

// fp32 -> bf16, 4 elements/thread
__global__ void cvt_f2bf(const float* __restrict__ in,
                         unsigned short* __restrict__ out, int n4) {
  int i = blockIdx.x * blockDim.x + threadIdx.x;
  if (i < n4) {
    float4 v = ((const float4*)in)[i];
    ushort4 o;
    o.x = f2bf(v.x); o.y = f2bf(v.y); o.z = f2bf(v.z); o.w = f2bf(v.w);
    ((ushort4*)out)[i] = o;
  }
}

// ---------------------------------------------------------------------------
// C[M,N] = A[M,K] * B[N,K]^T + bias[N]   (A,B bf16; bias fp32)
// mode 0: store fp32 to outf[M,N]
// mode 1: QKV split: n<512 -> qbuf; n<1024 -> kbuf; else transposed vtbuf[b][d][s]
//   (vt kv-chunks slot-permuted within each 32-kv block for attn's in-reg P)
// mode 2: A = merge(part0=A, part1=qbuf, mlbuf=(float2*)kbuf) fused in staging;
//   fp32 out like mode 0.  (replaces the old merge_halves kernel)
// 128x128 tile, BK=64, double-buffered LDS, ONE __syncthreads per K-step
// (T3-min: stage(kt+1) issued right after the barrier -> full phase of flight).
// LDS granule XOR swizzle (T2 / rule 21): linear global_load_lds dest, source
// granule pre-swizzled by (row&7); frag reads XOR by (c&7) -> 2-way (free)
// instead of the old 64B-row 8-way conflict.
// ---------------------------------------------------------------------------
__global__ __launch_bounds__(256, 2) void gemm_bt(
    const unsigned short* __restrict__ A, const unsigned short* __restrict__ B,
    const float* __restrict__ bias, float* __restrict__ outf,
    unsigned short* __restrict__ qbuf, unsigned short* __restrict__ kbuf,
    unsigned short* __restrict__ vtbuf, int M, int N, int K, int mode) {
  __shared__ alignas(16) unsigned short As[2 * 128 * 64];
  __shared__ alignas(16) unsigned short Bs[2 * 128 * 64];
  const int n0 = blockIdx.x * 128, m0 = blockIdx.y * 128;
  const int tid = threadIdx.x;
  const int l = tid & 63, w = tid >> 6;
  const int quad = l >> 4, c = l & 15;
  const int wm = (w >> 1) * 64, wn = (w & 1) * 64;
  const int srow = l >> 3;                    // 0..7 within wave's 8-row group
  const int gsw = (l & 7) ^ (srow & 7);       // pre-swizzled source granule
  const float C1m = 0.125f * LOG2E;

  const unsigned short* p1base = qbuf;            // mode 2: part1
  const float2* ml = (const float2*)kbuf;         // mode 2: mlbuf

  // stage one 128x64 tile pair into buffer bsel (16KB each)
  auto stage = [&](int kt, int bsel) {
    const int kk = kt * 64;
    const int lb = bsel * 8192;
#pragma unroll
    for (int i = 0; i < 4; ++i) {
      const int rb = i * 32 + w * 8;
      gld_lds16(&B[(size_t)(n0 + rb + srow) * K + kk + gsw * 8],
                &Bs[lb + rb * 64]);
      if (mode != 2) {
        gld_lds16(&A[(size_t)(m0 + rb + srow) * K + kk + gsw * 8],
                  &As[lb + rb * 64]);
      } else {
        // fused merge: A = w0*part0 + w1*part1 (reg-staged, swizzled ds_write)
        const int r = m0 + rb + srow;
        const bf16x8 v0 = ld_frag(&A[(size_t)r * K + kk + gsw * 8]);
        const bf16x8 v1 = ld_frag(&p1base[(size_t)r * K + kk + gsw * 8]);
        const float2 ma = ml[r];
        const float2 mb = ml[16384 + r];
        const float Mx = fmaxf(ma.x, mb.x);
        float w0 = ma.y * exp2f((ma.x - Mx) * C1m);
        float w1 = mb.y * exp2f((mb.x - Mx) * C1m);
        const float inv = 1.0f / (w0 + w1);
        w0 *= inv; w1 *= inv;
        union { bf16x8 v; ushort4 s4[2]; } pk;
#pragma unroll
        for (int e = 0; e < 8; ++e) {
          const float mv = w0 * (float)v0[e] + w1 * (float)v1[e];
          ((unsigned short*)&pk)[e] = f2bf(mv);
        }
        // linear slot position (row, l&7): content = logical granule gsw
        *(bf16x8*)&As[lb + (rb + srow) * 64 + (l & 7) * 8] = pk.v;
      }
    }
  };

  f32x4 acc[4][4] = {};
  const int kiters = K >> 6;
  stage(0, 0);
  for (int kt = 0; kt < kiters; ++kt) {
    __syncthreads();  // drains stage(kt) (vmcnt+lgkm) for all waves
    if (kt + 1 < kiters) stage(kt + 1, (kt + 1) & 1);
    const int lb = (kt & 1) * 8192;
#pragma unroll
    for (int ks = 0; ks < 2; ++ks) {
      bf16x8 af[4], bfr[4];
      const int gsel = ((ks * 4 + quad) ^ (c & 7)) * 8;
#pragma unroll
      for (int t = 0; t < 4; ++t) {
        af[t] = ld_frag(&As[lb + (wm + t * 16 + c) * 64 + gsel]);
        bfr[t] = ld_frag(&Bs[lb + (wn + t * 16 + c) * 64 + gsel]);
      }
#pragma unroll
      for (int mt = 0; mt < 4; ++mt)
#pragma unroll
        for (int nt = 0; nt < 4; ++nt)
          acc[mt][nt] = MFMA16(af[mt], bfr[nt], acc[mt][nt]);
    }
  }

#pragma unroll
  for (int nt = 0; nt < 4; ++nt) {
    const int n = n0 + wn + nt * 16 + c;
    const float bsum = bias[n];
#pragma unroll
    for (int mt = 0; mt < 4; ++mt) {
      const int mbase = m0 + wm + mt * 16 + quad * 4;
      if (mode != 1) {
#pragma unroll
        for (int r = 0; r < 4; ++r)
          outf[(size_t)(mbase + r) * N + n] = acc[mt][nt][r] + bsum;
      } else if (n < 1024) {
        unsigned short* dst = (n < 512) ? qbuf : kbuf;
        const int nn = n & 511;
#pragma unroll
        for (int r = 0; r < 4; ++r)
          dst[(size_t)(mbase + r) * 512 + nn] = f2bf(acc[mt][nt][r] + bsum);
      } else {
        const int d = n - 1024;
        const int bb = mbase >> 12, s = mbase & 4095;
        // slot-permute: chunk c=(s>>2)&7 -> position (c&3)*2 + (c>>2)
        const int cidx = (s >> 2) & 7;
        const int sp = (s & ~31) | (((((cidx & 3) << 1) | (cidx >> 2))) << 2);
        ushort4 pk;
        pk.x = f2bf(acc[mt][nt][0] + bsum);
        pk.y = f2bf(acc[mt][nt][1] + bsum);
        pk.z = f2bf(acc[mt][nt][2] + bsum);
        pk.w = f2bf(acc[mt][nt][3] + bsum);
        *(ushort4*)&vtbuf[((size_t)bb * 512 + d) * 4096 + sp] = pk;
      }
    }
  }
}

// ---------------------------------------------------------------------------
// Flash attention (round-5 structure, unchanged): transposed-S, kv-split-2,
// q-split PV with P in registers; V rows slot-permuted by gemm1.
// ---------------------------------------------------------------------------
#define KROW 520

__global__ __launch_bounds__(256, 2) void attn_kernel(
    const unsigned short* __restrict__ Q, const unsigned short* __restrict__ Kb,
    const unsigned short* __restrict__ Vt, unsigned short* __restrict__ part0,
    unsigned short* __restrict__ part1, float2* __restrict__ mlbuf) {
  __shared__ alignas(16) unsigned short k_lds[32 * KROW];
  __shared__ alignas(16) unsigned short v_lds[512 * 32];

  const int bid = blockIdx.x;
  const int xcd = bid & 7;
  const int b = xcd >> 1;                          // 2 XCDs per batch
  const int half = (bid >> 3) & 1;                 // kv half
  const int qt = (bid >> 4) | ((xcd & 1) << 5);    // 0..63
  const int s0 = qt * 64;
  const int kvbase = half * 2048;
  const int tid = threadIdx.x;
  const int l = tid & 63, w = tid >> 6;
  const int quad = l >> 4, c = l & 15;
  const size_t boff = (size_t)b * 4096 * 512;

  const unsigned short* Kbase = Kb + boff;
  const unsigned short* Vbase = Vt + (size_t)b * 512 * 4096;

  auto stage_k = [&](int kv0) {
#pragma unroll
    for (int i = 0; i < 8; ++i) {  // K: one 1KB row per wave per call
      const int row = i * 4 + w;
      gld_lds16(&Kbase[(size_t)(kv0 + row) * 512 + l * 8], &k_lds[row * KROW]);
    }
  };
  auto stage_v = [&](int kv0) {
#pragma unroll
    for (int i = 0; i < 8; ++i) {  // Vt: XOR-swizzled 16B granules
      const int dbase = (i * 4 + w) * 16;
      const int d = dbase + (l >> 2);
      const int jl = (l & 3) ^ ((d >> 1) & 3);
      gld_lds16(&Vbase[(size_t)d * 4096 + kv0 + jl * 8], &v_lds[dbase * 32]);
    }
  };

  stage_k(kvbase);
  stage_v(kvbase);

  // Q fragments pinned (B-operand layout: col = c, k = quad*8+j)
  bf16x8 qf[16];
  {
    const unsigned short* qrow = Q + boff + (size_t)(s0 + w * 16 + c) * 512;
#pragma unroll
    for (int ks = 0; ks < 16; ++ks) qf[ks] = ld_frag(&qrow[ks * 32 + quad * 8]);
  }

  // O^T, q-split: o[t] holds [d = t*16 + quad*4 + r][q = w*16 + c]
  f32x4 o[32] = {};
  float m_run = -1e30f, l_run = 0.f;  // per-lane (q = w*16+c), repl. over quads

  const float C1 = 0.125f * LOG2E;
  const int jp8 = (quad ^ ((c >> 1) & 3)) * 8;  // V read swizzle (t-indep)

  for (int it = 0; it < 64; ++it) {
    // --- bar1: K(it) landed (vmcnt(8): the 8 newest = V(it), still flying)
    asm volatile("s_waitcnt vmcnt(8)" ::: "memory");
    __builtin_amdgcn_sched_barrier(0);
    __builtin_amdgcn_s_barrier();
    __builtin_amdgcn_sched_barrier(0);

    // --- S^T = K Q^T (A = K frag, B = Q frag; identical lane layouts)
    f32x4 sa[2][2] = {};
    __builtin_amdgcn_s_setprio(1);
#pragma unroll
    for (int ks = 0; ks < 16; ++ks) {
      const unsigned short* kr = &k_lds[c * KROW + ks * 32 + quad * 8];
      bf16x8 kf0 = ld_frag(kr);
      bf16x8 kf1 = ld_frag(kr + 16 * KROW);
      sa[0][ks & 1] = MFMA16(kf0, qf[ks], sa[0][ks & 1]);
      sa[1][ks & 1] = MFMA16(kf1, qf[ks], sa[1][ks & 1]);
    }
    __builtin_amdgcn_s_setprio(0);
    const f32x4 s0v = sa[0][0] + sa[0][1];  // kv = quad*4+r, q = w*16+c
    const f32x4 s1v = sa[1][0] + sa[1][1];  // kv = 16+quad*4+r

    // --- bar2: own k reads retired + own V(it) landed -> k_lds free, V ready
    asm volatile("s_waitcnt vmcnt(0) lgkmcnt(0)" ::: "memory");
    __builtin_amdgcn_sched_barrier(0);
    __builtin_amdgcn_s_barrier();
    __builtin_amdgcn_sched_barrier(0);

    if (it + 1 < 64) stage_k(kvbase + (it + 1) * 32);  // flies over SM+PV+QK

    // --- online softmax (own 16 q): in-lane + 2 cross-quad shuffles
    float m8 = fmaxf(fmaxf(fmaxf(s0v[0], s0v[1]), fmaxf(s0v[2], s0v[3])),
                     fmaxf(fmaxf(s1v[0], s1v[1]), fmaxf(s1v[2], s1v[3])));
    m8 = fmaxf(m8, __shfl_xor(m8, 16));
    m8 = fmaxf(m8, __shfl_xor(m8, 32));

    // defer-max (T13): rescale only when tile max grows > 8 raw units
    const bool need = __any(m8 - m_run > 8.0f);
    if (need) {
      const float mn = fmaxf(m_run, m8);
      const float alpha = exp2f((m_run - mn) * C1);
      m_run = mn;
      l_run *= alpha;
#pragma unroll
      for (int t = 0; t < 32; ++t) o[t] *= alpha;
    }

    float p0[4], p1[4], s8 = 0.f;
#pragma unroll
    for (int r = 0; r < 4; ++r) {
      p0[r] = exp2f((s0v[r] - m_run) * C1);
      p1[r] = exp2f((s1v[r] - m_run) * C1);
      s8 += p0[r] + p1[r];
    }
    s8 += __shfl_xor(s8, 16);
    s8 += __shfl_xor(s8, 32);
    l_run += s8;

    // P fragment IN-REGISTER: slot quad*8+j -> kv {4q+j, 16+4q+(j-4)}
    union { bf16x8 v; unsigned u[4]; } pfu;
    pfu.u[0] = (unsigned)f2bf(p0[0]) | ((unsigned)f2bf(p0[1]) << 16);
    pfu.u[1] = (unsigned)f2bf(p0[2]) | ((unsigned)f2bf(p0[3]) << 16);
    pfu.u[2] = (unsigned)f2bf(p1[0]) | ((unsigned)f2bf(p1[1]) << 16);
    pfu.u[3] = (unsigned)f2bf(p1[2]) | ((unsigned)f2bf(p1[3]) << 16);
    const bf16x8 pf = pfu.v;

    // --- O^T += V^T P^T: A = slot-permuted V granule (one b128), B = pf
    __builtin_amdgcn_s_setprio(1);
#pragma unroll
    for (int t = 0; t < 32; ++t) {
      const bf16x8 vf = ld_frag(&v_lds[(t * 16 + c) * 32 + jp8]);
      o[t] = MFMA16(vf, pf, o[t]);
    }
    __builtin_amdgcn_s_setprio(0);

    // --- bar3: own v reads retired -> v_lds free block-wide
    asm volatile("s_waitcnt lgkmcnt(0)" ::: "memory");
    __builtin_amdgcn_sched_barrier(0);
    __builtin_amdgcn_s_barrier();
    __builtin_amdgcn_sched_barrier(0);

    if (it + 1 < 64) stage_v(kvbase + (it + 1) * 32);  // flies over QK(it+1)
  }

  // epilogue: everything wave-local; write normalized partial + (m,l)
  const float inv = 1.0f / l_run;
  unsigned short* part = half ? part1 : part0;
  unsigned short* orow = part + boff + (size_t)(s0 + w * 16 + c) * 512;
#pragma unroll
  for (int t = 0; t < 32; ++t) {
    ushort4 pk;
    pk.x = f2bf(o[t][0] * inv);
    pk.y = f2bf(o[t][1] * inv);
    pk.z = f2bf(o[t][2] * inv);
    pk.w = f2bf(o[t][3] * inv);
    *(ushort4*)&orow[t * 16 + quad * 4] = pk;
  }
  if (quad == 0) {
    float2 ml; ml.x = m_run; ml.y = l_run;
    mlbuf[(size_t)half * 16384 + b * 4096 + s0 + w * 16 + c] = ml;
  }
}

// ---------------------------------------------------------------------------
extern "C" void kernel_launch(void* const* d_in, const int* in_sizes, int n_in,
                              void* d_out, int out_size, void* d_ws, size_t ws_size,
                              hipStream_t stream) {
  const float* x = (const float*)d_in[0];      // [4,4096,512] fp32
  const float* w_in = (const float*)d_in[1];   // [1536,512] fp32
  const float* b_in = (const float*)d_in[2];   // [1536] fp32
  const float* w_out = (const float*)d_in[3];  // [512,512] fp32
  const float* b_out = (const float*)d_in[4];  // [512] fp32
  float* out = (float*)d_out;                  // [4,4096,512] fp32

  const size_t MTOT = (size_t)4 * 4096 * 512;  // 8,388,608
  unsigned short* q = (unsigned short*)d_ws;
  unsigned short* k = q + MTOT;
  unsigned short* vt = k + MTOT;        // [b][d][s], kv-chunk slot-permuted
  unsigned short* xbf = vt + MTOT;      // x bf16 -> attn part0
  unsigned short* part1 = xbf + MTOT;   // attn part1
  unsigned short* w_in_bf = part1 + MTOT;
  unsigned short* w_out_bf = w_in_bf + 1536 * 512;
  float2* mlbuf = (float2*)(w_out_bf + 512 * 512);  // 2 x 16384 float2

  cvt_f2bf<<<dim3((int)(MTOT / 4 / 256)), 256, 0, stream>>>(x, xbf,
                                                            (int)(MTOT / 4));
  cvt_f2bf<<<dim3(768), 256, 0, stream>>>(w_in, w_in_bf, 1536 * 512 / 4);
  cvt_f2bf<<<dim3(256), 256, 0, stream>>>(w_out, w_out_bf, 512 * 512 / 4);

  gemm_bt<<<dim3(12, 128), 256, 0, stream>>>(xbf, w_in_bf, b_in, nullptr, q, k,
                                             vt, 16384, 1536, 512, 1);
  // flash attention, kv-split-2 (part0 overwrites xbf; x is dead)
  attn_kernel<<<dim3(512), 256, 0, stream>>>(q, k, vt, xbf, part1, mlbuf);
  // out = merge(part0,part1) @ w_out^T + b_out  (merge fused into A-staging)
  gemm_bt<<<dim3(4, 128), 256, 0, stream>>>(xbf, w_out_bf, b_out, out, part1,
                                            (unsigned short*)mlbuf, nullptr,
                                            16384, 512, 512, 2);
}